// Round 11
// baseline (198.601 us; speedup 1.0000x reference)
//
#include <hip/hip_runtime.h>
#include <math.h>

#define BATCH 4
#define SEQ   2048
#define DIN   1024
#define KVH   4
#define HD    64
#define MTOT  (BATCH*SEQ)          // 8192
#define NPROJ 768                  // [q_eff | k | v] columns
#define NCHUNK_TOT 80              // per bh: sum over qt of ceil((qt+1)/8)

typedef unsigned short ushort_t;
typedef __attribute__((ext_vector_type(8))) short short8;
typedef __attribute__((ext_vector_type(4))) float f32x4;

// fold 1/sqrt(64) and log2(e) into Q so softmax can use exp2
#define QSCALE (0.125f * 1.44269504088896340736f)

__device__ inline ushort_t f2bf(float x) {
    union { float f; unsigned int u; } v; v.f = x;
    unsigned int r = v.u + 0x7fffu + ((v.u >> 16) & 1u);   // RNE
    return (ushort_t)(r >> 16);
}
__device__ inline ushort_t f2bf_trunc(float x) {
    return (ushort_t)(__float_as_uint(x) >> 16);           // P only: cheap trunc
}
__device__ inline float bf2f(ushort_t x) {
    union { unsigned int u; float f; } v; v.u = ((unsigned int)x) << 16;
    return v.f;
}

// ---------------- fused prep: pack weights + ctab + q->bf16 -------------------
__global__ __launch_bounds__(256) void prep_kernel(
        const float* __restrict__ Wq, const float* __restrict__ Wk,
        const float* __restrict__ Wv, const float* __restrict__ Wo,
        const float* __restrict__ X,
        ushort_t* __restrict__ Wcat_t, ushort_t* __restrict__ Wo_t,
        float2* __restrict__ ctab, ushort_t* __restrict__ Y) {
    const int bx = blockIdx.x;
    const int tid = threadIdx.x;
    if (bx < 4096) {
        int idx = bx * 256 + tid;
        if (idx < NPROJ * DIN) {
            int n = idx >> 10, k = idx & 1023;
            float v;
            if (n < 256) {
                const float* p = Wq + (size_t)k * 1024 + (n >> 6) * 256 + (n & 63);
                v = p[0] + p[64] + p[128] + p[192];
            } else if (n < 512) {
                v = Wk[(size_t)k * 256 + (n - 256)];
            } else {
                v = Wv[(size_t)k * 256 + (n - 512)];
            }
            Wcat_t[idx] = f2bf(v);
        } else {
            int t = idx - NPROJ * DIN;
            int n = t >> 8, k = t & 255;
            Wo_t[t] = f2bf(Wo[(size_t)k * 1024 + n]);
        }
    } else if (bx < 4352) {
        int t = (bx - 4096) * 256 + tid;      // 65536: s x 32 table
        int j = t & 31, s = t >> 5;
        float ang = (float)(s + 1) * exp10f(-(float)j);
        float sn, cs;
        sincosf(ang, &sn, &cs);
        ctab[t] = make_float2(cs, sn);
    } else {
        int i = ((bx - 4352) * 256 + tid) * 4;   // 8M f32 -> bf16
        float4 v = *(const float4*)&X[i];
        ushort4 o;
        o.x = f2bf(v.x); o.y = f2bf(v.y); o.z = f2bf(v.z); o.w = f2bf(v.w);
        *(ushort4*)&Y[i] = o;
    }
}

// ---------------- bf16 MFMA GEMM (proj): 128x64 tile, BK=64 -------------------
// Round-9 version (direct-store epilogue; round-10 LDS transpose regressed).
// Fused RoPE epilogue: q -> Qbf (scaled), k -> Kbf, v -> bf16 Vt [bh][d][s].
__global__ __launch_bounds__(256) void proj_mfma_kernel(
        const ushort_t* __restrict__ A, const ushort_t* __restrict__ Bt,
        ushort_t* __restrict__ Qbf, ushort_t* __restrict__ Kbf,
        ushort_t* __restrict__ Vt, const float2* __restrict__ ctab) {
    const int K = DIN, N = NPROJ;
    __shared__ __align__(16) ushort_t As[128 * 64];   // 16 KB, swizzled
    __shared__ __align__(16) ushort_t Bs[64 * 64];    //  8 KB
    const int tid  = threadIdx.x;
    const int w    = tid >> 6, lane = tid & 63;
    const int m15  = lane & 15, quad = lane >> 4;
    const int wm   = (w >> 1) * 64, wn = (w & 1) * 32;
    const int m0   = blockIdx.y * 128, n0 = blockIdx.x * 64;
    const int r8   = lane >> 3;
    const int c8   = (lane & 7) * 8;
    const int cs   = (((lane & 7) + r8) & 7) * 8;
    const int rotr = (m15 & 7) * 8;
    const int off0 = (quad * 8 + 64 - rotr) & 63;
    const int off1 = (32 + quad * 8 + 64 - rotr) & 63;

    const int niter = K >> 6;                         // 16
    const int kst   = blockIdx.y & (niter - 1);

    f32x4 acc[4][2];
    #pragma unroll
    for (int i = 0; i < 4; ++i)
        #pragma unroll
        for (int j = 0; j < 2; ++j) acc[i][j] = (f32x4){0.f, 0.f, 0.f, 0.f};

    short8 ra[4], rb[2];
    {
        const int k0 = kst * 64;
        #pragma unroll
        for (int p = 0; p < 4; ++p)
            ra[p] = *(const short8*)(A + (size_t)(m0 + w * 32 + p * 8 + r8) * K + k0 + cs);
        #pragma unroll
        for (int p = 0; p < 2; ++p)
            rb[p] = *(const short8*)(Bt + (size_t)(n0 + w * 16 + p * 8 + r8) * K + k0 + cs);
    }

    for (int it = 0; it < niter; ++it) {
        __syncthreads();
        #pragma unroll
        for (int p = 0; p < 4; ++p)
            *(short8*)&As[(w * 32 + p * 8 + r8) * 64 + c8] = ra[p];
        #pragma unroll
        for (int p = 0; p < 2; ++p)
            *(short8*)&Bs[(w * 16 + p * 8 + r8) * 64 + c8] = rb[p];
        __syncthreads();

        if (it + 1 < niter) {
            const int kn = ((kst + it + 1) & (niter - 1)) * 64;
            #pragma unroll
            for (int p = 0; p < 4; ++p)
                ra[p] = *(const short8*)(A + (size_t)(m0 + w * 32 + p * 8 + r8) * K + kn + cs);
            #pragma unroll
            for (int p = 0; p < 2; ++p)
                rb[p] = *(const short8*)(Bt + (size_t)(n0 + w * 16 + p * 8 + r8) * K + kn + cs);
        }

        short8 af[4][2], bfm[2][2];
        #pragma unroll
        for (int i = 0; i < 4; ++i) {
            af[i][0] = *(const short8*)&As[(wm + i * 16 + m15) * 64 + off0];
            af[i][1] = *(const short8*)&As[(wm + i * 16 + m15) * 64 + off1];
        }
        #pragma unroll
        for (int j = 0; j < 2; ++j) {
            bfm[j][0] = *(const short8*)&Bs[(wn + j * 16 + m15) * 64 + off0];
            bfm[j][1] = *(const short8*)&Bs[(wn + j * 16 + m15) * 64 + off1];
        }
        #pragma unroll
        for (int i = 0; i < 4; ++i)
            #pragma unroll
            for (int j = 0; j < 2; ++j) {
                acc[i][j] = __builtin_amdgcn_mfma_f32_16x16x32_bf16(
                                af[i][0], bfm[j][0], acc[i][j], 0, 0, 0);
                acc[i][j] = __builtin_amdgcn_mfma_f32_16x16x32_bf16(
                                af[i][1], bfm[j][1], acc[i][j], 0, 0, 0);
            }
    }

    #pragma unroll
    for (int j = 0; j < 2; ++j) {
        int c = n0 + wn + j * 16 + m15;     // 0..767 (proj uniform per wave)
        int proj = c >> 8, cc = c & 255;
        int hd = cc >> 6, d = cc & 63;
        if (proj < 2) {
            // fused RoPE: partner element (d^1) lives in the xor-1 lane
            int jj = d >> 1;
            float sgn = (d & 1) ? 1.0f : -1.0f;
            float qs  = (proj == 0) ? QSCALE : 1.0f;
            ushort_t* dst = (proj ? Kbf : Qbf) + (size_t)hd * SEQ * HD + d;
            #pragma unroll
            for (int i = 0; i < 4; ++i)
                #pragma unroll
                for (int r = 0; r < 4; ++r) {
                    int m = m0 + wm + i * 16 + quad * 4 + r;
                    int b = m >> 11, s = m & (SEQ - 1);
                    float x = acc[i][j][r];
                    float p = __shfl_xor(x, 1);
                    float2 ct = ctab[s * 32 + jj];
                    float o = (x * ct.x + sgn * p * ct.y) * qs;
                    dst[(((size_t)b * KVH) * SEQ + s) * HD] = f2bf(o);
                }
        } else {
            // V: straight to transposed bf16 [bh][d][s]
            ushort_t* Vp = Vt + (((size_t)hd * HD) + d) * SEQ;
            #pragma unroll
            for (int i = 0; i < 4; ++i)
                #pragma unroll
                for (int r = 0; r < 4; ++r) {
                    int m = m0 + wm + i * 16 + quad * 4 + r;
                    int b = m >> 11, s = m & (SEQ - 1);
                    Vp[(size_t)b * KVH * HD * SEQ + s] = f2bf(acc[i][j][r]);
                }
        }
    }
}

// ---------------- MFMA flash attention, split-K, pipelined staging ------------
// pO partials now bf16 (halved traffic).
__global__ __launch_bounds__(256) void attn_mfma_kernel(
        const ushort_t* __restrict__ Qbf, const ushort_t* __restrict__ Kbf,
        const ushort_t* __restrict__ Vtbf, ushort_t* __restrict__ pO,
        float* __restrict__ pL) {
    __shared__ __align__(16) ushort_t Ks[64][72];
    __shared__ __align__(16) ushort_t Vts[64][72];
    __shared__ __align__(16) ushort_t Ps[4][16][72];
    const int tid  = threadIdx.x;
    const int w    = tid >> 6, lane = tid & 63;
    const int m15  = lane & 15, quad = lane >> 4;
    const int bh   = blockIdx.y;
    const int f    = 79 - blockIdx.x;           // heavy chunks first
    int qt, ch;
    if (f < 8)       { qt = f;                    ch = 0; }
    else if (f < 24) { qt = 8  + ((f - 8) >> 1);  ch = (f - 8) & 1; }
    else if (f < 48) { qt = 16 + (f - 24) / 3;    ch = (f - 24) % 3; }
    else             { qt = 24 + ((f - 48) >> 2); ch = (f - 48) & 3; }
    const int q0 = qt * 64;
    const int kt_beg = ch * 8;
    const int kt_end = min(kt_beg + 8, qt + 1);

    const ushort_t* Qb  = Qbf  + (size_t)bh * SEQ * HD;
    const ushort_t* Kb  = Kbf  + (size_t)bh * SEQ * HD;
    const ushort_t* Vtb = Vtbf + (size_t)bh * HD * SEQ;

    const int qrow = q0 + w * 16 + m15;
    short8 qf0 = *(const short8*)(Qb + (size_t)qrow * HD + quad * 8);
    short8 qf1 = *(const short8*)(Qb + (size_t)qrow * HD + 32 + quad * 8);

    f32x4 o[4];
    #pragma unroll
    for (int nt = 0; nt < 4; ++nt) o[nt] = (f32x4){0.f, 0.f, 0.f, 0.f};
    float lacc[4] = {0.f, 0.f, 0.f, 0.f};

    const int sc_ = tid & 7;       // stage: 16B chunk
    const int sr_ = tid >> 3;      // stage: row 0..31

    short8 pk0, pk1, pv0, pv1;
    {
        const int k0 = kt_beg * 64;
        pk0 = *(const short8*)(Kb  + (size_t)(k0 + sr_) * HD + sc_ * 8);
        pk1 = *(const short8*)(Kb  + (size_t)(k0 + sr_ + 32) * HD + sc_ * 8);
        pv0 = *(const short8*)(Vtb + (size_t)sr_ * SEQ + k0 + sc_ * 8);
        pv1 = *(const short8*)(Vtb + (size_t)(sr_ + 32) * SEQ + k0 + sc_ * 8);
    }

    for (int kt = kt_beg; kt < kt_end; ++kt) {
        const int k0 = kt * 64;
        __syncthreads();
        *(short8*)&Ks[sr_][sc_*8]       = pk0;
        *(short8*)&Ks[sr_ + 32][sc_*8]  = pk1;
        *(short8*)&Vts[sr_][sc_*8]      = pv0;
        *(short8*)&Vts[sr_ + 32][sc_*8] = pv1;
        __syncthreads();

        if (kt + 1 < kt_end) {     // post-barrier prefetch: drains next iter
            const int kn = k0 + 64;
            pk0 = *(const short8*)(Kb  + (size_t)(kn + sr_) * HD + sc_ * 8);
            pk1 = *(const short8*)(Kb  + (size_t)(kn + sr_ + 32) * HD + sc_ * 8);
            pv0 = *(const short8*)(Vtb + (size_t)sr_ * SEQ + kn + sc_ * 8);
            pv1 = *(const short8*)(Vtb + (size_t)(sr_ + 32) * SEQ + kn + sc_ * 8);
        }

        f32x4 sc4[4];
        #pragma unroll
        for (int nt = 0; nt < 4; ++nt) {
            f32x4 c = {0.f, 0.f, 0.f, 0.f};
            c = __builtin_amdgcn_mfma_f32_16x16x32_bf16(
                    qf0, *(const short8*)&Ks[nt*16 + m15][quad*8], c, 0, 0, 0);
            c = __builtin_amdgcn_mfma_f32_16x16x32_bf16(
                    qf1, *(const short8*)&Ks[nt*16 + m15][32 + quad*8], c, 0, 0, 0);
            sc4[nt] = c;
        }
        if (kt == qt) {            // diagonal tile: causal mask
            #pragma unroll
            for (int nt = 0; nt < 4; ++nt) {
                int colg = k0 + nt*16 + m15;
                #pragma unroll
                for (int r = 0; r < 4; ++r) {
                    int rowg = q0 + w*16 + quad*4 + r;
                    if (colg > rowg) sc4[nt][r] = -INFINITY;
                }
            }
        }

        #pragma unroll
        for (int nt = 0; nt < 4; ++nt)
            #pragma unroll
            for (int r = 0; r < 4; ++r) {
                float e = exp2f(sc4[nt][r]);
                lacc[r] += e;
                Ps[w][quad*4 + r][nt*16 + m15] = f2bf_trunc(e);
            }

        short8 pa0 = *(const short8*)&Ps[w][m15][quad*8];
        short8 pa1 = *(const short8*)&Ps[w][m15][32 + quad*8];
        #pragma unroll
        for (int nt = 0; nt < 4; ++nt) {
            o[nt] = __builtin_amdgcn_mfma_f32_16x16x32_bf16(
                        pa0, *(const short8*)&Vts[nt*16 + m15][quad*8], o[nt], 0, 0, 0);
            o[nt] = __builtin_amdgcn_mfma_f32_16x16x32_bf16(
                        pa1, *(const short8*)&Vts[nt*16 + m15][32 + quad*8], o[nt], 0, 0, 0);
        }
    }

    const int blk = bh * NCHUNK_TOT + f;
    #pragma unroll
    for (int r = 0; r < 4; ++r) {
        float ls = lacc[r];
        ls += __shfl_xor(ls, 1);
        ls += __shfl_xor(ls, 2);
        ls += __shfl_xor(ls, 4);
        ls += __shfl_xor(ls, 8);
        int row = w * 16 + quad * 4 + r;
        if (m15 == 0) pL[(size_t)blk * 64 + row] = ls;
        #pragma unroll
        for (int nt = 0; nt < 4; ++nt)
            pO[(size_t)blk * 4096 + row * 64 + nt * 16 + m15] = f2bf(o[nt][r]);
    }
}

// ---------------- fused combine + output projection ---------------------------
// grid: 128 blocks, one per (b, 64-row s-tile). Phase 1: sum bf16 partials /
// normalize -> bf16 A-tile (64x256) in LDS. Phase 2: K=256 GEMM vs Wo_t in
// 16 n-chunks of 64 (Wo chunk staged in LDS), writing f32 d_out directly.
// Deletes the attn_bf round-trip and one kernel launch.
__device__ inline int flat_of(int qt, int ch) {
    if (qt < 8)  return qt;
    if (qt < 16) return 8 + (qt - 8) * 2 + ch;
    if (qt < 24) return 24 + (qt - 16) * 3 + ch;
    return 48 + (qt - 24) * 4 + ch;
}

__global__ __launch_bounds__(256) void combine_outproj_kernel(
        const ushort_t* __restrict__ pO, const float* __restrict__ pL,
        const ushort_t* __restrict__ Wo_t, float* __restrict__ Out) {
    __shared__ __align__(16) ushort_t As2[64 * 264];   // A: 64 rows x 256 k (pad 8)
    __shared__ __align__(16) ushort_t Bs2[64 * 264];   // Wo chunk: 64 n x 256 k
    const int tid  = threadIdx.x;
    const int w    = tid >> 6, lane = tid & 63;
    const int m15  = lane & 15, quad = lane >> 4;
    const int b    = blockIdx.x >> 5;
    const int qt   = blockIdx.x & 31;
    const int nch  = (qt >> 3) + 1;

    // ---- phase 1: build normalized A-tile ----
    {
        const int row = tid >> 2;          // 0..63
        const int qtr = tid & 3;           // 16-col group within a head
        #pragma unroll
        for (int h = 0; h < 4; ++h) {
            const int bh = b * KVH + h;
            float acc[16] = {};
            float lsum = 0.f;
            for (int c = 0; c < nch; ++c) {
                int blk = bh * NCHUNK_TOT + flat_of(qt, c);
                const ushort_t* po = pO + (size_t)blk * 4096 + row * 64 + qtr * 16;
                lsum += pL[(size_t)blk * 64 + row];
                ushort_t raw[16];
                *(uint4*)raw       = *(const uint4*)po;
                *(uint4*)(raw + 8) = *(const uint4*)(po + 8);
                #pragma unroll
                for (int u = 0; u < 16; ++u) acc[u] += bf2f(raw[u]);
            }
            float inv = 1.0f / lsum;
            ushort_t outv[16];
            #pragma unroll
            for (int u = 0; u < 16; ++u) outv[u] = f2bf(acc[u] * inv);
            ushort_t* dst = &As2[row * 264 + h * 64 + qtr * 16];
            *(uint4*)dst       = ((uint4*)outv)[0];
            *(uint4*)(dst + 8) = ((uint4*)outv)[1];
        }
    }
    __syncthreads();

    // ---- A-fragments into registers: wave w owns rows [w*16, w*16+16) ----
    short8 af2[8];
    #pragma unroll
    for (int ks = 0; ks < 8; ++ks)
        af2[ks] = *(const short8*)&As2[(w * 16 + m15) * 264 + ks * 32 + quad * 8];

    const size_t outbase = ((size_t)b * SEQ + qt * 64 + w * 16) * DIN;

    // ---- phase 2: 16 n-chunks of 64 ----
    const int srow = tid >> 2;             // Wo stage: row 0..63
    const int sqtr = tid & 3;              // 64-k group
    for (int nc = 0; nc < 16; ++nc) {
        const int n0 = nc * 64;
        __syncthreads();                   // prev chunk's B reads done
        #pragma unroll
        for (int u = 0; u < 8; ++u)
            *(short8*)&Bs2[srow * 264 + sqtr * 64 + u * 8] =
                *(const short8*)(Wo_t + (size_t)(n0 + srow) * 256 + sqtr * 64 + u * 8);
        __syncthreads();

        f32x4 acc2[4];
        #pragma unroll
        for (int j = 0; j < 4; ++j) acc2[j] = (f32x4){0.f, 0.f, 0.f, 0.f};
        #pragma unroll
        for (int ks = 0; ks < 8; ++ks) {
            #pragma unroll
            for (int j = 0; j < 4; ++j) {
                short8 bfj = *(const short8*)&Bs2[(j * 16 + m15) * 264 + ks * 32 + quad * 8];
                acc2[j] = __builtin_amdgcn_mfma_f32_16x16x32_bf16(
                              af2[ks], bfj, acc2[j], 0, 0, 0);
            }
        }
        #pragma unroll
        for (int j = 0; j < 4; ++j)
            #pragma unroll
            for (int r = 0; r < 4; ++r)
                Out[outbase + (size_t)(quad * 4 + r) * DIN + n0 + j * 16 + m15] =
                    acc2[j][r];
    }
}

extern "C" void kernel_launch(void* const* d_in, const int* in_sizes, int n_in,
                              void* d_out, int out_size, void* d_ws, size_t ws_size,
                              hipStream_t stream) {
    const float* q  = (const float*)d_in[0];
    // d_in[1] = mask (tril) — causality hardcoded
    const float* Wq = (const float*)d_in[2];
    const float* Wk = (const float*)d_in[3];
    const float* Wv = (const float*)d_in[4];
    const float* Wo = (const float*)d_in[5];
    float* out = (float*)d_out;

    // workspace layout (byte offsets; aliases are temporally disjoint):
    //   0x0000000 wcat_t  (1.5MB)
    //   0x0180000 wo_t    (0.5MB)
    //   0x0200000 ctab    (0.5MB)
    //   0x0280000 qin_bf  (16MB) [dead after proj]
    //   0x0680000 pO bf16 (10.5MB) [over dead qin tail]
    //   0x1A80000 pL      (320KB)
    //   0x1B00000 q_bf    (4MB)
    //   0x1F00000 k_bf    (4MB)
    //   0x2300000 vt_bf   (4MB)   -> peak 39MB
    char* base = (char*)d_ws;
    ushort_t* wcat_t  = (ushort_t*)(base);
    ushort_t* wo_t    = (ushort_t*)(base + 0x180000);
    float2*   ctab    = (float2*)(base + 0x200000);
    ushort_t* qin_bf  = (ushort_t*)(base + 0x280000);
    ushort_t* pO      = (ushort_t*)(base + 0x680000);
    float*    pL      = (float*)(base + 0x1A80000);
    ushort_t* q_bf    = (ushort_t*)(base + 0x1B00000);
    ushort_t* k_bf    = (ushort_t*)(base + 0x1F00000);
    ushort_t* vt_bf   = (ushort_t*)(base + 0x2300000);

    // 1. fused prep: pack weights + ctab + q->bf16
    prep_kernel<<<12544, 256, 0, stream>>>(Wq, Wk, Wv, Wo, q,
                                           wcat_t, wo_t, ctab, qin_bf);

    // 2. QKV projection with fused RoPE: q->Qbf(scaled), k->Kbf, v->Vt, all bf16
    dim3 gproj(NPROJ / 64, MTOT / 128);    // (12, 64) = 768 blocks, 3/CU
    proj_mfma_kernel<<<gproj, 256, 0, stream>>>(
        qin_bf, wcat_t, q_bf, k_bf, vt_bf, ctab);

    // 3. split-K MFMA causal attention -> bf16 partials
    dim3 gattn(NCHUNK_TOT, BATCH * KVH);   // (80, 16): 5 blocks/CU, all resident
    attn_mfma_kernel<<<gattn, 256, 0, stream>>>(q_bf, k_bf, vt_bf, pO, pL);

    // 4. fused combine + output projection -> f32 out
    combine_outproj_kernel<<<MTOT / 64, 256, 0, stream>>>(pO, pL, wo_t, out);
}

// Round 12
// 172.563 us; speedup vs baseline: 1.1509x; 1.1509x over previous
//
#include <hip/hip_runtime.h>
#include <math.h>

#define BATCH 4
#define SEQ   2048
#define DIN   1024
#define KVH   4
#define HD    64
#define MTOT  (BATCH*SEQ)          // 8192
#define NPROJ 768                  // [q_eff | k | v] columns
#define NCHUNK_TOT 80              // per bh: sum over qt of ceil((qt+1)/8)

typedef unsigned short ushort_t;
typedef __attribute__((ext_vector_type(8))) short short8;
typedef __attribute__((ext_vector_type(4))) float f32x4;

// fold 1/sqrt(64) and log2(e) into Q so softmax can use exp2
#define QSCALE (0.125f * 1.44269504088896340736f)

__device__ inline ushort_t f2bf(float x) {
    union { float f; unsigned int u; } v; v.f = x;
    unsigned int r = v.u + 0x7fffu + ((v.u >> 16) & 1u);   // RNE
    return (ushort_t)(r >> 16);
}
__device__ inline ushort_t f2bf_trunc(float x) {
    return (ushort_t)(__float_as_uint(x) >> 16);           // P only: cheap trunc
}
__device__ inline float bf2f(ushort_t x) {
    union { unsigned int u; float f; } v; v.u = ((unsigned int)x) << 16;
    return v.f;
}

// ---------------- fused prep: pack weights + ctab + q->bf16 -------------------
__global__ __launch_bounds__(256) void prep_kernel(
        const float* __restrict__ Wq, const float* __restrict__ Wk,
        const float* __restrict__ Wv, const float* __restrict__ Wo,
        const float* __restrict__ X,
        ushort_t* __restrict__ Wcat_t, ushort_t* __restrict__ Wo_t,
        float2* __restrict__ ctab, ushort_t* __restrict__ Y) {
    const int bx = blockIdx.x;
    const int tid = threadIdx.x;
    if (bx < 4096) {
        int idx = bx * 256 + tid;
        if (idx < NPROJ * DIN) {
            int n = idx >> 10, k = idx & 1023;
            float v;
            if (n < 256) {
                const float* p = Wq + (size_t)k * 1024 + (n >> 6) * 256 + (n & 63);
                v = p[0] + p[64] + p[128] + p[192];
            } else if (n < 512) {
                v = Wk[(size_t)k * 256 + (n - 256)];
            } else {
                v = Wv[(size_t)k * 256 + (n - 512)];
            }
            Wcat_t[idx] = f2bf(v);
        } else {
            int t = idx - NPROJ * DIN;
            int n = t >> 8, k = t & 255;
            Wo_t[t] = f2bf(Wo[(size_t)k * 1024 + n]);
        }
    } else if (bx < 4352) {
        int t = (bx - 4096) * 256 + tid;      // 65536: s x 32 table
        int j = t & 31, s = t >> 5;
        float ang = (float)(s + 1) * exp10f(-(float)j);
        float sn, cs;
        sincosf(ang, &sn, &cs);
        ctab[t] = make_float2(cs, sn);
    } else {
        int i = ((bx - 4352) * 256 + tid) * 4;   // 8M f32 -> bf16
        float4 v = *(const float4*)&X[i];
        ushort4 o;
        o.x = f2bf(v.x); o.y = f2bf(v.y); o.z = f2bf(v.z); o.w = f2bf(v.w);
        *(ushort4*)&Y[i] = o;
    }
}

// ---------------- bf16 MFMA GEMM: 128x64 tile, BK=64, pipelined ---------------
// Round-9 K-loop (reg-prefetch post-barrier, swizzled conflict-free LDS).
// 1D grid + XCD-aware swizzle: work = (bid%8)*WORKS + bid/8 so all n-tiles of
// one A-strip land on one XCD -> A re-reads served from that XCD's 4MB L2.
// OUT_MODE 0: Y f32 row-major MxN (outproj: NTILES=16, K=256).
// OUT_MODE 1: proj (NTILES=12, K=1024), fused RoPE epilogue:
//             q -> Qbf (scaled), k -> Kbf, v -> bf16 Vt [bh][d][s].
template<int OUT_MODE, int NTILES, int WORKS>
__global__ __launch_bounds__(256) void gemm_mfma_kernel(
        const ushort_t* __restrict__ A, const ushort_t* __restrict__ Bt,
        float* __restrict__ Y, ushort_t* __restrict__ Qbf,
        ushort_t* __restrict__ Kbf, ushort_t* __restrict__ Vt,
        const float2* __restrict__ ctab, int K, int N) {
    __shared__ __align__(16) ushort_t As[128 * 64];   // 16 KB, swizzled
    __shared__ __align__(16) ushort_t Bs[64 * 64];    //  8 KB
    const int tid  = threadIdx.x;
    const int w    = tid >> 6, lane = tid & 63;
    const int m15  = lane & 15, quad = lane >> 4;
    const int wm   = (w >> 1) * 64, wn = (w & 1) * 32;
    const int bid  = blockIdx.x;
    const int work = (bid & 7) * WORKS + (bid >> 3);  // XCD-locality remap
    const int mten = work / NTILES, nten = work - mten * NTILES;
    const int m0   = mten * 128, n0 = nten * 64;
    const int r8   = lane >> 3;
    const int c8   = (lane & 7) * 8;
    const int cs   = (((lane & 7) + r8) & 7) * 8;
    const int rotr = (m15 & 7) * 8;
    const int off0 = (quad * 8 + 64 - rotr) & 63;
    const int off1 = (32 + quad * 8 + 64 - rotr) & 63;

    const int niter = K >> 6;
    const int kst   = mten & (niter - 1);             // desync start phase

    f32x4 acc[4][2];
    #pragma unroll
    for (int i = 0; i < 4; ++i)
        #pragma unroll
        for (int j = 0; j < 2; ++j) acc[i][j] = (f32x4){0.f, 0.f, 0.f, 0.f};

    short8 ra[4], rb[2];
    {
        const int k0 = kst * 64;
        #pragma unroll
        for (int p = 0; p < 4; ++p)
            ra[p] = *(const short8*)(A + (size_t)(m0 + w * 32 + p * 8 + r8) * K + k0 + cs);
        #pragma unroll
        for (int p = 0; p < 2; ++p)
            rb[p] = *(const short8*)(Bt + (size_t)(n0 + w * 16 + p * 8 + r8) * K + k0 + cs);
    }

    for (int it = 0; it < niter; ++it) {
        __syncthreads();
        #pragma unroll
        for (int p = 0; p < 4; ++p)
            *(short8*)&As[(w * 32 + p * 8 + r8) * 64 + c8] = ra[p];
        #pragma unroll
        for (int p = 0; p < 2; ++p)
            *(short8*)&Bs[(w * 16 + p * 8 + r8) * 64 + c8] = rb[p];
        __syncthreads();

        if (it + 1 < niter) {      // post-barrier prefetch: lands during compute
            const int kn = ((kst + it + 1) & (niter - 1)) * 64;
            #pragma unroll
            for (int p = 0; p < 4; ++p)
                ra[p] = *(const short8*)(A + (size_t)(m0 + w * 32 + p * 8 + r8) * K + kn + cs);
            #pragma unroll
            for (int p = 0; p < 2; ++p)
                rb[p] = *(const short8*)(Bt + (size_t)(n0 + w * 16 + p * 8 + r8) * K + kn + cs);
        }

        short8 af[4][2], bfm[2][2];
        #pragma unroll
        for (int i = 0; i < 4; ++i) {
            af[i][0] = *(const short8*)&As[(wm + i * 16 + m15) * 64 + off0];
            af[i][1] = *(const short8*)&As[(wm + i * 16 + m15) * 64 + off1];
        }
        #pragma unroll
        for (int j = 0; j < 2; ++j) {
            bfm[j][0] = *(const short8*)&Bs[(wn + j * 16 + m15) * 64 + off0];
            bfm[j][1] = *(const short8*)&Bs[(wn + j * 16 + m15) * 64 + off1];
        }
        #pragma unroll
        for (int i = 0; i < 4; ++i)
            #pragma unroll
            for (int j = 0; j < 2; ++j) {
                acc[i][j] = __builtin_amdgcn_mfma_f32_16x16x32_bf16(
                                af[i][0], bfm[j][0], acc[i][j], 0, 0, 0);
                acc[i][j] = __builtin_amdgcn_mfma_f32_16x16x32_bf16(
                                af[i][1], bfm[j][1], acc[i][j], 0, 0, 0);
            }
    }

    if (OUT_MODE == 0) {
        #pragma unroll
        for (int i = 0; i < 4; ++i)
            #pragma unroll
            for (int r = 0; r < 4; ++r) {
                size_t row = (size_t)(m0 + wm + i * 16 + quad * 4 + r);
                #pragma unroll
                for (int j = 0; j < 2; ++j)
                    Y[row * N + n0 + wn + j * 16 + m15] = acc[i][j][r];
            }
    } else {
        #pragma unroll
        for (int j = 0; j < 2; ++j) {
            int c = n0 + wn + j * 16 + m15;     // 0..767 (proj uniform per wave)
            int proj = c >> 8, cc = c & 255;
            int hd = cc >> 6, d = cc & 63;
            if (proj < 2) {
                // fused RoPE: partner element (d^1) lives in the xor-1 lane
                int jj = d >> 1;
                float sgn = (d & 1) ? 1.0f : -1.0f;
                float qs  = (proj == 0) ? QSCALE : 1.0f;
                ushort_t* dst = (proj ? Kbf : Qbf) + (size_t)hd * SEQ * HD + d;
                #pragma unroll
                for (int i = 0; i < 4; ++i)
                    #pragma unroll
                    for (int r = 0; r < 4; ++r) {
                        int m = m0 + wm + i * 16 + quad * 4 + r;
                        int b = m >> 11, s = m & (SEQ - 1);
                        float x = acc[i][j][r];
                        float p = __shfl_xor(x, 1);
                        float2 ct = ctab[s * 32 + jj];
                        float o = (x * ct.x + sgn * p * ct.y) * qs;
                        dst[(((size_t)b * KVH) * SEQ + s) * HD] = f2bf(o);
                    }
            } else {
                // V: straight to transposed bf16 [bh][d][s]
                ushort_t* Vp = Vt + (((size_t)hd * HD) + d) * SEQ;
                #pragma unroll
                for (int i = 0; i < 4; ++i)
                    #pragma unroll
                    for (int r = 0; r < 4; ++r) {
                        int m = m0 + wm + i * 16 + quad * 4 + r;
                        int b = m >> 11, s = m & (SEQ - 1);
                        Vp[(size_t)b * KVH * HD * SEQ + s] = f2bf(acc[i][j][r]);
                    }
            }
        }
    }
}

// ---------------- MFMA flash attention, split-K, pipelined staging ------------
// 1D grid 1280 + XCD swizzle: each XCD owns 2 bh (K/V ~8MB, mostly L2-resident),
// processing its 80-chunk stream heavy-first. bf16 pO partials.
__global__ __launch_bounds__(256) void attn_mfma_kernel(
        const ushort_t* __restrict__ Qbf, const ushort_t* __restrict__ Kbf,
        const ushort_t* __restrict__ Vtbf, ushort_t* __restrict__ pO,
        float* __restrict__ pL) {
    __shared__ __align__(16) ushort_t Ks[64][72];
    __shared__ __align__(16) ushort_t Vts[64][72];
    __shared__ __align__(16) ushort_t Ps[4][16][72];
    const int tid  = threadIdx.x;
    const int w    = tid >> 6, lane = tid & 63;
    const int m15  = lane & 15, quad = lane >> 4;
    const int bid  = blockIdx.x;
    const int work = (bid & 7) * 160 + (bid >> 3);    // XCD-locality remap
    const int bh   = work / 80;
    const int f    = 79 - (work - bh * 80);           // heavy chunks first
    int qt, ch;
    if (f < 8)       { qt = f;                    ch = 0; }
    else if (f < 24) { qt = 8  + ((f - 8) >> 1);  ch = (f - 8) & 1; }
    else if (f < 48) { qt = 16 + (f - 24) / 3;    ch = (f - 24) % 3; }
    else             { qt = 24 + ((f - 48) >> 2); ch = (f - 48) & 3; }
    const int q0 = qt * 64;
    const int kt_beg = ch * 8;
    const int kt_end = min(kt_beg + 8, qt + 1);

    const ushort_t* Qb  = Qbf  + (size_t)bh * SEQ * HD;
    const ushort_t* Kb  = Kbf  + (size_t)bh * SEQ * HD;
    const ushort_t* Vtb = Vtbf + (size_t)bh * HD * SEQ;

    const int qrow = q0 + w * 16 + m15;
    short8 qf0 = *(const short8*)(Qb + (size_t)qrow * HD + quad * 8);
    short8 qf1 = *(const short8*)(Qb + (size_t)qrow * HD + 32 + quad * 8);

    f32x4 o[4];
    #pragma unroll
    for (int nt = 0; nt < 4; ++nt) o[nt] = (f32x4){0.f, 0.f, 0.f, 0.f};
    float lacc[4] = {0.f, 0.f, 0.f, 0.f};

    const int sc_ = tid & 7;       // stage: 16B chunk
    const int sr_ = tid >> 3;      // stage: row 0..31

    short8 pk0, pk1, pv0, pv1;
    {
        const int k0 = kt_beg * 64;
        pk0 = *(const short8*)(Kb  + (size_t)(k0 + sr_) * HD + sc_ * 8);
        pk1 = *(const short8*)(Kb  + (size_t)(k0 + sr_ + 32) * HD + sc_ * 8);
        pv0 = *(const short8*)(Vtb + (size_t)sr_ * SEQ + k0 + sc_ * 8);
        pv1 = *(const short8*)(Vtb + (size_t)(sr_ + 32) * SEQ + k0 + sc_ * 8);
    }

    for (int kt = kt_beg; kt < kt_end; ++kt) {
        const int k0 = kt * 64;
        __syncthreads();
        *(short8*)&Ks[sr_][sc_*8]       = pk0;
        *(short8*)&Ks[sr_ + 32][sc_*8]  = pk1;
        *(short8*)&Vts[sr_][sc_*8]      = pv0;
        *(short8*)&Vts[sr_ + 32][sc_*8] = pv1;
        __syncthreads();

        if (kt + 1 < kt_end) {     // post-barrier prefetch: drains next iter
            const int kn = k0 + 64;
            pk0 = *(const short8*)(Kb  + (size_t)(kn + sr_) * HD + sc_ * 8);
            pk1 = *(const short8*)(Kb  + (size_t)(kn + sr_ + 32) * HD + sc_ * 8);
            pv0 = *(const short8*)(Vtb + (size_t)sr_ * SEQ + kn + sc_ * 8);
            pv1 = *(const short8*)(Vtb + (size_t)(sr_ + 32) * SEQ + kn + sc_ * 8);
        }

        f32x4 sc4[4];
        #pragma unroll
        for (int nt = 0; nt < 4; ++nt) {
            f32x4 c = {0.f, 0.f, 0.f, 0.f};
            c = __builtin_amdgcn_mfma_f32_16x16x32_bf16(
                    qf0, *(const short8*)&Ks[nt*16 + m15][quad*8], c, 0, 0, 0);
            c = __builtin_amdgcn_mfma_f32_16x16x32_bf16(
                    qf1, *(const short8*)&Ks[nt*16 + m15][32 + quad*8], c, 0, 0, 0);
            sc4[nt] = c;
        }
        if (kt == qt) {            // diagonal tile: causal mask
            #pragma unroll
            for (int nt = 0; nt < 4; ++nt) {
                int colg = k0 + nt*16 + m15;
                #pragma unroll
                for (int r = 0; r < 4; ++r) {
                    int rowg = q0 + w*16 + quad*4 + r;
                    if (colg > rowg) sc4[nt][r] = -INFINITY;
                }
            }
        }

        #pragma unroll
        for (int nt = 0; nt < 4; ++nt)
            #pragma unroll
            for (int r = 0; r < 4; ++r) {
                float e = exp2f(sc4[nt][r]);
                lacc[r] += e;
                Ps[w][quad*4 + r][nt*16 + m15] = f2bf_trunc(e);
            }

        short8 pa0 = *(const short8*)&Ps[w][m15][quad*8];
        short8 pa1 = *(const short8*)&Ps[w][m15][32 + quad*8];
        #pragma unroll
        for (int nt = 0; nt < 4; ++nt) {
            o[nt] = __builtin_amdgcn_mfma_f32_16x16x32_bf16(
                        pa0, *(const short8*)&Vts[nt*16 + m15][quad*8], o[nt], 0, 0, 0);
            o[nt] = __builtin_amdgcn_mfma_f32_16x16x32_bf16(
                        pa1, *(const short8*)&Vts[nt*16 + m15][32 + quad*8], o[nt], 0, 0, 0);
        }
    }

    const int blk = bh * NCHUNK_TOT + f;
    #pragma unroll
    for (int r = 0; r < 4; ++r) {
        float ls = lacc[r];
        ls += __shfl_xor(ls, 1);
        ls += __shfl_xor(ls, 2);
        ls += __shfl_xor(ls, 4);
        ls += __shfl_xor(ls, 8);
        int row = w * 16 + quad * 4 + r;
        if (m15 == 0) pL[(size_t)blk * 64 + row] = ls;
        #pragma unroll
        for (int nt = 0; nt < 4; ++nt)
            pO[(size_t)blk * 4096 + row * 64 + nt * 16 + m15] = f2bf(o[nt][r]);
    }
}

// ---------------- combine: sum bf16 chunk partials, normalize, emit bf16 ------
__device__ inline int flat_of(int qt, int ch) {
    if (qt < 8)  return qt;
    if (qt < 16) return 8 + (qt - 8) * 2 + ch;
    if (qt < 24) return 24 + (qt - 16) * 3 + ch;
    return 48 + (qt - 24) * 4 + ch;
}

__global__ __launch_bounds__(256) void combine_kernel(
        const ushort_t* __restrict__ pO, const float* __restrict__ pL,
        ushort_t* __restrict__ Out) {
    const int qt = blockIdx.x, bh = blockIdx.y;
    const int tid = threadIdx.x;
    const int row = tid >> 2;
    const int cb = (tid & 3) * 16;
    const int nch = (qt >> 3) + 1;
    float acc[16] = {};
    float lsum = 0.f;
    for (int c = 0; c < nch; ++c) {
        int blk = bh * NCHUNK_TOT + flat_of(qt, c);
        const ushort_t* po = pO + (size_t)blk * 4096 + row * 64 + cb;
        lsum += pL[(size_t)blk * 64 + row];
        ushort_t raw[16];
        *(uint4*)raw       = *(const uint4*)po;
        *(uint4*)(raw + 8) = *(const uint4*)(po + 8);
        #pragma unroll
        for (int u = 0; u < 16; ++u) acc[u] += bf2f(raw[u]);
    }
    float inv = 1.0f / lsum;
    int b = bh >> 2, h = bh & 3;
    int s = qt * 64 + row;
    ushort_t tmp[16];
    #pragma unroll
    for (int j = 0; j < 16; ++j) tmp[j] = f2bf(acc[j] * inv);
    ushort_t* dst = Out + ((size_t)b * SEQ + s) * (KVH * HD) + h * HD + cb;
    *(uint4*)dst = ((uint4*)tmp)[0];
    *(uint4*)(dst + 8) = ((uint4*)tmp)[1];
}

extern "C" void kernel_launch(void* const* d_in, const int* in_sizes, int n_in,
                              void* d_out, int out_size, void* d_ws, size_t ws_size,
                              hipStream_t stream) {
    const float* q  = (const float*)d_in[0];
    // d_in[1] = mask (tril) — causality hardcoded
    const float* Wq = (const float*)d_in[2];
    const float* Wk = (const float*)d_in[3];
    const float* Wv = (const float*)d_in[4];
    const float* Wo = (const float*)d_in[5];
    float* out = (float*)d_out;

    // workspace layout (byte offsets; aliases are temporally disjoint):
    //   0x0000000 wcat_t  (1.5MB)
    //   0x0180000 wo_t    (0.5MB)
    //   0x0200000 ctab    (0.5MB)
    //   0x0280000 qin_bf  (16MB) [dead after proj]; attn_bf aliases first 4MB
    //   0x0680000 pO bf16 (10.5MB) [over dead qin tail]
    //   0x1A80000 pL      (320KB)
    //   0x1B00000 q_bf    (4MB)
    //   0x1F00000 k_bf    (4MB)
    //   0x2300000 vt_bf   (4MB)   -> peak 39MB
    char* base = (char*)d_ws;
    ushort_t* wcat_t  = (ushort_t*)(base);
    ushort_t* wo_t    = (ushort_t*)(base + 0x180000);
    float2*   ctab    = (float2*)(base + 0x200000);
    ushort_t* qin_bf  = (ushort_t*)(base + 0x280000);
    ushort_t* attn_bf = (ushort_t*)(base + 0x280000);   // alias (qin dead by then)
    ushort_t* pO      = (ushort_t*)(base + 0x680000);
    float*    pL      = (float*)(base + 0x1A80000);
    ushort_t* q_bf    = (ushort_t*)(base + 0x1B00000);
    ushort_t* k_bf    = (ushort_t*)(base + 0x1F00000);
    ushort_t* vt_bf   = (ushort_t*)(base + 0x2300000);

    // 1. fused prep: pack weights + ctab + q->bf16
    prep_kernel<<<12544, 256, 0, stream>>>(Wq, Wk, Wv, Wo, q,
                                           wcat_t, wo_t, ctab, qin_bf);

    // 2. QKV projection with fused RoPE (XCD-swizzled 1D grid: 768 blocks)
    gemm_mfma_kernel<1, 12, 96><<<768, 256, 0, stream>>>(
        qin_bf, wcat_t, nullptr, q_bf, k_bf, vt_bf, ctab, DIN, NPROJ);

    // 3. split-K MFMA causal attention -> bf16 partials (XCD-swizzled, 1280)
    attn_mfma_kernel<<<1280, 256, 0, stream>>>(q_bf, k_bf, vt_bf, pO, pL);

    // 4. combine partials -> normalized bf16 attn_out [b][s][h*64+d]
    dim3 gcomb(SEQ / 64, BATCH * KVH);     // (32, 16)
    combine_kernel<<<gcomb, 256, 0, stream>>>(pO, pL, attn_bf);

    // 5. output projection (XCD-swizzled 1D grid: 1024 blocks) -> f32 out
    gemm_mfma_kernel<0, 16, 128><<<1024, 256, 0, stream>>>(
        attn_bf, wo_t, out, nullptr, nullptr, nullptr, nullptr, KVH * HD, DIN);
}